// Round 11
// baseline (3934.142 us; speedup 1.0000x reference)
//
#include <hip/hip_runtime.h>

#define TT 512
#define BB 64
#define EE 300
#define HH 1024
#define GG 4096
#define NSLOT 33   // h ring; flags give per-step lockstep, WAR distance >= 32

typedef _Float16 f16x8 __attribute__((ext_vector_type(8)));
typedef float f32x4 __attribute__((ext_vector_type(4)));

// Workspace:
//   flags @0, 4 KB                  flags[p]: step counters
//   hbuf  @4096, NSLOT x 131072 B   [slot][kb32][quad4][b64][j8] f16
//   mask  @off_mask, 512*64*4       [t][b]
//   xA    @off_xA, 512*20480*2      [t][kb10][quad][b64][j8] f16

__device__ __forceinline__ float sigmf(float x) {
    return __fdividef(1.0f, 1.0f + __expf(-x));
}
__device__ __forceinline__ float tanhsf(float x) {
    float e = __expf(-2.0f * fabsf(x));
    float r = __fdividef(1.0f - e, 1.0f + e);
    return copysignf(r, x);
}

__global__ void mask_kernel(const int* __restrict__ seq, float* __restrict__ maskf) {
    int idx = blockIdx.x * 256 + threadIdx.x;   // 512*64
    int t = idx >> 6, b = idx & 63;
    maskf[idx] = (seq[b * TT + t] != 0) ? 1.0f : 0.0f;
}

// xA[t][kb][quad][b][j] = f16(emb[seq[b][t]][e]), e = kb*32+quad*8+j (r7 layout)
__global__ __launch_bounds__(256)
void xgather_kernel(const float* __restrict__ emb, const int* __restrict__ seq,
                    _Float16* __restrict__ xA) {
    __shared__ float xrow[64 * 305];
    const int t = blockIdx.x, tid = threadIdx.x;
    const int r = tid >> 2, sub = tid & 3;
    const int row = seq[r * TT + t];
    for (int e = sub; e < EE; e += 4)
        xrow[r * 305 + e] = emb[row * EE + e];
    __syncthreads();
    unsigned int* dst = (unsigned int*)(xA + (size_t)t * 20480);
    for (int idx = tid; idx < 10240; idx += 256) {
        int el = idx << 1;
        int j = el & 7, b = (el >> 3) & 63, quad = (el >> 9) & 3, kb = el >> 11;
        int e = (kb << 5) + (quad << 3) + j;
        union { _Float16 h[2]; unsigned int u; } pk;
        pk.h[0] = (e < EE)     ? (_Float16)xrow[b * 305 + e]     : (_Float16)0.f;
        pk.h[1] = (e + 1 < EE) ? (_Float16)xrow[b * 305 + e + 1] : (_Float16)0.f;
        dst[idx] = pk.u;
    }
}

// Persistent LSTM: 256 WGs x 512 thr (8 waves; 1 WG/CU via ~84KB LDS).
// r10 post-mortem: keep r7's wave parallelism + cheap flat flags, but overlap
// step t's serial tail with step t+1's head. Wave 0 = gates/publish/flag
// (c/h state in registers, 28 ds_read_b128 reduce, 8B/lane publish, private
// vmcnt(0)); waves 1-7 = K-split h.R + x.W (B-frags in registers), polling
// only their 32-40 producers. ONE __syncthreads per step; zb double-buffered
// by parity (barrier N: partials(N-1) ready -> w0 gates(N-1) || w1-7
// partials(N)). No LDS spin handshakes (r9 lesson), no extra pollsets (r10).
__global__ __launch_bounds__(512, 2)
void lstm_kernel(const _Float16* __restrict__ xA, const float* __restrict__ rk,
                 const float* __restrict__ wk, const float* __restrict__ bias,
                 const float* __restrict__ maskf, _Float16* __restrict__ hbuf,
                 unsigned int* __restrict__ flags, float* __restrict__ out) {
    __shared__ union {
        struct { _Float16 Rb[16384]; _Float16 Wb[5120]; } st;  // staging 43008 B
        float zbl[2][7][1280];                                  // [par][wi][b*20+c]
    } U;                                                        // 71680 B
    __shared__ float padL[3200];   // force 1 WG/CU (>80KB total), volatile-kept
    const int tid = threadIdx.x;
    const int lane = tid & 63;
    const int w = tid >> 6;
    const int p = blockIdx.x;
    const int p4 = p << 2;
    const int cc = lane & 15, quad = lane >> 4;

    ((volatile float*)padL)[tid] = 0.f;

    // stage B-fragments of R and W (f16), once
    for (int i = tid; i < 16384; i += 512) {
        int k = i >> 4, c = i & 15;
        float v = rk[k * GG + ((c >> 2) << 10) + p4 + (c & 3)];
        U.st.Rb[((k >> 5) << 9) + (((k >> 3) & 3) << 7) + (c << 3) + (k & 7)] = (_Float16)v;
    }
    for (int i = tid; i < 5120; i += 512) {
        int e = i >> 4, c = i & 15;
        float v = (e < EE) ? wk[e * GG + ((c >> 2) << 10) + p4 + (c & 3)] : 0.f;
        U.st.Wb[((e >> 5) << 9) + (((e >> 3) & 3) << 7) + (c << 3) + (e & 7)] = (_Float16)v;
    }
    __syncthreads();   // barrier #1 (staging complete)

    if (w == 0) {
        // ================= gates / publish / flag wave =================
        float bbi[4], bbf[4], bbg[4], bbo[4];
#pragma unroll
        for (int u = 0; u < 4; ++u) {
            bbi[u] = bias[p4 + u];
            bbf[u] = bias[1024 + p4 + u];
            bbg[u] = bias[2048 + p4 + u];
            bbo[u] = bias[3072 + p4 + u];
        }
        float cst[4] = {0.f, 0.f, 0.f, 0.f};
        float hwv[4] = {0.f, 0.f, 0.f, 0.f};
        const size_t pub_base = ((size_t)(p >> 3) << 9) + ((size_t)((p >> 1) & 3) << 7)
                                + ((size_t)lane << 1) + (size_t)(p & 1);
        __syncthreads();   // barrier #2 (pairs with compute waves' frag-load barrier)
        int pslot = 1;     // slot of h^{t+1}
        for (int t = 0; t < TT; ++t) {
            __syncthreads();   // barrier #(3+t): partials(t) in zbl[t&1] ready
            float m = maskf[(t << 6) + lane];
            const float* zr = &U.zbl[t & 1][0][0] + lane * 20;
            float sacc[16];
#pragma unroll
            for (int q4 = 0; q4 < 4; ++q4) {
                f32x4 v = *(const f32x4*)(zr + (q4 << 2));
#pragma unroll
                for (int wi2 = 1; wi2 < 7; ++wi2)
                    v += *(const f32x4*)(zr + wi2 * 1280 + (q4 << 2));
                sacc[(q4 << 2) + 0] = v[0]; sacc[(q4 << 2) + 1] = v[1];
                sacc[(q4 << 2) + 2] = v[2]; sacc[(q4 << 2) + 3] = v[3];
            }
            union { _Float16 hp[4]; unsigned long long u64; } pk;
#pragma unroll
            for (int u = 0; u < 4; ++u) {
                float zi = sacc[u] + bbi[u];
                float zf = sacc[4 + u] + bbf[u];
                float zg = sacc[8 + u] + bbg[u];
                float zo = sacc[12 + u] + bbo[u];
                float fi = sigmf(zi);
                float ff = sigmf(zf);
                float fg = tanhsf(zg);
                float fo = sigmf(zo);
                float cn = fmaf(ff, cst[u], fi * fg);
                cn = fmaf(m, cn - cst[u], cst[u]);     // masked c update
                cst[u] = cn;
                float hc = fo * tanhsf(cn);
                hwv[u] = fmaf(m, hc - hwv[u], hwv[u]); // masked h update
                pk.hp[u] = (_Float16)hwv[u];
            }
            __hip_atomic_store((unsigned long long*)hbuf + (size_t)pslot * 16384 + pub_base,
                               pk.u64, __ATOMIC_RELAXED, __HIP_MEMORY_SCOPE_AGENT);
            __asm__ volatile("s_waitcnt vmcnt(0)" ::: "memory");  // publish acked
            if (lane == 0)
                __hip_atomic_store(flags + p, (unsigned)(t + 1),
                                   __ATOMIC_RELAXED, __HIP_MEMORY_SCOPE_AGENT);
            pslot = (pslot + 1 == NSLOT) ? 0 : pslot + 1;
        }
        *(float4*)(out + lane * HH + p4) =
            make_float4(hwv[0], hwv[1], hwv[2], hwv[3]);
    } else {
        // ================= compute waves 1..7: K-split h.R + x.W =================
        const int wi = w - 1;
        const int rec0 = (wi < 4) ? wi * 5 : 20 + ((wi - 4) << 2);
        const int nrec = (wi < 4) ? 5 : 4;
        const int xw0  = (wi < 4) ? wi : 4 + ((wi - 4) << 1);
        const int nxw  = (wi < 4) ? 1 : 2;
        f16x8 bR[5], bW[2];
#pragma unroll
        for (int r = 0; r < 5; ++r) if (r < nrec)
            bR[r] = *(const f16x8*)(U.st.Rb + ((rec0 + r) << 9) + (quad << 7) + (cc << 3));
#pragma unroll
        for (int xi = 0; xi < 2; ++xi) if (xi < nxw)
            bW[xi] = *(const f16x8*)(U.st.Wb + ((xw0 + xi) << 9) + (quad << 7) + (cc << 3));
        const int nprod = nrec << 3;
        const int fl = (rec0 << 3) + ((lane < nprod) ? lane : nprod - 1);
        __syncthreads();   // barrier #2: frags in regs, staging LDS reusable as zbl

        int ps = 0;        // slot of h^s
        for (int s = 0; s < TT; ++s) {
            f32x4 acc[4];
#pragma unroll
            for (int mt = 0; mt < 4; ++mt) acc[mt] = (f32x4){0.f, 0.f, 0.f, 0.f};
            // x.W(s): no remote dep, overlaps the flag poll
            const f16x8* xt8 = (const f16x8*)(xA + (size_t)s * 20480);
#pragma unroll
            for (int xi = 0; xi < 2; ++xi) if (xi < nxw) {
                const int kb = xw0 + xi;
#pragma unroll
                for (int mt = 0; mt < 4; ++mt) {
                    f16x8 af = xt8[(kb << 8) + (quad << 6) + (mt << 4) + cc];
                    acc[mt] = __builtin_amdgcn_mfma_f32_16x16x32_f16(af, bW[xi], acc[mt], 0, 0, 0);
                }
            }
            // poll my producers: h^s published (s=0 trivially true)
            {
                unsigned tgt = (unsigned)s;
                while (!__all((int)(__hip_atomic_load(flags + fl, __ATOMIC_RELAXED,
                                                      __HIP_MEMORY_SCOPE_AGENT) >= tgt)))
                    __builtin_amdgcn_s_sleep(1);
            }
            __builtin_amdgcn_sched_barrier(0);
            const f16x8* hp8 = (const f16x8*)hbuf + (size_t)ps * 8192;
#pragma unroll
            for (int r = 0; r < 5; ++r) if (r < nrec) {
                const int kb = rec0 + r;
#pragma unroll
                for (int mt = 0; mt < 4; ++mt) {
                    f16x8 af = hp8[(kb << 8) + (quad << 6) + (mt << 4) + cc];
                    acc[mt] = __builtin_amdgcn_mfma_f32_16x16x32_f16(af, bR[r], acc[mt], 0, 0, 0);
                }
            }
            // C layout: col=cc, row b = mt*16 + quad*4 + i  ->  zbl[s&1][wi][b*20+cc]
            float* zw = &U.zbl[s & 1][wi][0];
#pragma unroll
            for (int mt = 0; mt < 4; ++mt)
#pragma unroll
                for (int i = 0; i < 4; ++i)
                    zw[((mt << 4) + (quad << 2) + i) * 20 + cc] = acc[mt][i];
            ps = (ps + 1 == NSLOT) ? 0 : ps + 1;
            __syncthreads();   // barrier #(3+s): zbl[s] published to wave 0
        }
    }
}

extern "C" void kernel_launch(void* const* d_in, const int* in_sizes, int n_in,
                              void* d_out, int out_size, void* d_ws, size_t ws_size,
                              hipStream_t stream) {
    const float* emb  = (const float*)d_in[0];
    const float* wk   = (const float*)d_in[1];
    const float* rk   = (const float*)d_in[2];
    const float* bias = (const float*)d_in[3];
    const int*   seq  = (const int*)d_in[4];
    float* out = (float*)d_out;
    char* ws = (char*)d_ws;

    const size_t off_hbuf = 4096;
    const size_t off_mask = off_hbuf + (size_t)NSLOT * 131072;
    const size_t off_xA   = off_mask + 131072;
    unsigned int* flags = (unsigned int*)ws;
    _Float16* hbuf  = (_Float16*)(ws + off_hbuf);
    float*    maskf = (float*)(ws + off_mask);
    _Float16* xA    = (_Float16*)(ws + off_xA);

    // zero flags + hbuf slot 0 (contiguous prefix); ws is re-poisoned each call
    hipMemsetAsync(ws, 0, off_hbuf + 131072, stream);
    mask_kernel<<<128, 256, 0, stream>>>(seq, maskf);
    xgather_kernel<<<TT, 256, 0, stream>>>(emb, seq, xA);
    lstm_kernel<<<256, 512, 0, stream>>>(xA, rk, wk, bias, maskf, hbuf, flags, out);
}